// Round 2
// baseline (345.285 us; speedup 1.0000x reference)
//
#include <hip/hip_runtime.h>

// Problem constants: B=8, H=W=1024, V=35709, T=70789
#define BATCH 8
#define HWPIX (1024 * 1024)
#define NVERT 35709
#define NTRI  70789

// ---------------------------------------------------------------------------
// Prep: build per-(batch,triangle) corner-color table in ws.
// Record: 3 float4 = 48B: q0=(c0.r,c0.g,c0.b,0) q1=(c1...) q2=(c2...)
// Collapses the two-level gather (tid->tris->colors) into one level.
// ---------------------------------------------------------------------------
__global__ __launch_bounds__(256) void build_tritab(
    const float* __restrict__ colors,  // [B,V,3]
    const int*   __restrict__ tris,    // [T,3]
    float4*      __restrict__ tab)     // [B,T,3] float4
{
    const int t = blockIdx.x * blockDim.x + threadIdx.x;
    const int b = blockIdx.y;
    if (t >= NTRI) return;
    const int v0 = tris[3 * t + 0];
    const int v1 = tris[3 * t + 1];
    const int v2 = tris[3 * t + 2];
    const float* cb = colors + (long long)b * (3 * NVERT);
    const float* c0 = cb + 3 * v0;
    const float* c1 = cb + 3 * v1;
    const float* c2 = cb + 3 * v2;
    float4* rec = tab + ((long long)b * NTRI + t) * 3;
    rec[0] = make_float4(c0[0], c0[1], c0[2], 0.0f);
    rec[1] = make_float4(c1[0], c1[1], c1[2], 0.0f);
    rec[2] = make_float4(c2[0], c2[1], c2[2], 0.0f);
}

// ---------------------------------------------------------------------------
// Main: one thread = 4 horizontally-adjacent pixels. Streamed I/O is 16B
// vectorized; per-pixel gather is exactly 3 float4 loads from the table.
// ---------------------------------------------------------------------------
__global__ __launch_bounds__(256) void raster_tab_kernel(
    const int*    __restrict__ tids,   // [B,H,W]
    const float*  __restrict__ bary,   // [B,H,W,3]
    const float4* __restrict__ tab,    // [B,T,3] float4
    float*        __restrict__ out)    // images [B,3,H,W] ++ alphas [B,1,H,W]
{
    const long long q  = (long long)blockIdx.x * blockDim.x + threadIdx.x;
    const long long p0 = q << 2;
    const int b  = (int)(p0 >> 20);
    const int hw = (int)(p0 & (HWPIX - 1));

    const int4 t4 = ((const int4*)tids)[q];

    const float4 bv0 = ((const float4*)bary)[q * 3 + 0];
    const float4 bv1 = ((const float4*)bary)[q * 3 + 1];
    const float4 bv2 = ((const float4*)bary)[q * 3 + 2];

    const float w0[4] = {bv0.x, bv0.w, bv1.z, bv2.y};
    const float w1[4] = {bv0.y, bv1.x, bv1.w, bv2.z};
    const float w2[4] = {bv0.z, bv1.y, bv2.x, bv2.w};
    const int  tid[4] = {t4.x, t4.y, t4.z, t4.w};

    const float4* tb = tab + (long long)b * (3 * NTRI);

    float r[4], g[4], bl[4], a[4];
#pragma unroll
    for (int i = 0; i < 4; ++i) {
        const float4* rec = tb + 3 * tid[i];
        const float4 c0 = rec[0];
        const float4 c1 = rec[1];
        const float4 c2 = rec[2];
        const float u0 = w0[i], u1 = w1[i], u2 = w2[i];
        r[i]  = fminf(fmaxf(c0.x * u0 + c1.x * u1 + c2.x * u2, 0.0f), 1.0f);
        g[i]  = fminf(fmaxf(c0.y * u0 + c1.y * u1 + c2.y * u2, 0.0f), 1.0f);
        bl[i] = fminf(fmaxf(c0.z * u0 + c1.z * u1 + c2.z * u2, 0.0f), 1.0f);
        a[i]  = fminf(fmaxf(2.0f * (u0 + u1 + u2), 0.0f), 1.0f);
    }

    float* img = out + (long long)b * (3 * HWPIX) + hw;
    ((float4*)(img            ))[0] = make_float4(r[0],  r[1],  r[2],  r[3]);
    ((float4*)(img +     HWPIX))[0] = make_float4(g[0],  g[1],  g[2],  g[3]);
    ((float4*)(img + 2 * HWPIX))[0] = make_float4(bl[0], bl[1], bl[2], bl[3]);

    float* al = out + (long long)BATCH * 3 * HWPIX + (long long)b * HWPIX + hw;
    ((float4*)al)[0] = make_float4(a[0], a[1], a[2], a[3]);
}

// ---------------------------------------------------------------------------
// Fallback (R1 kernel): direct two-level gather, used only if ws is too small.
// ---------------------------------------------------------------------------
__global__ __launch_bounds__(256) void raster_kernel(
    const int*   __restrict__ tids,
    const float* __restrict__ bary,
    const float* __restrict__ colors,
    const int*   __restrict__ tris,
    float*       __restrict__ out)
{
    const long long q  = (long long)blockIdx.x * blockDim.x + threadIdx.x;
    const long long p0 = q << 2;
    const int b  = (int)(p0 >> 20);
    const int hw = (int)(p0 & (HWPIX - 1));

    const int4 t4 = ((const int4*)tids)[q];
    const float4 bv0 = ((const float4*)bary)[q * 3 + 0];
    const float4 bv1 = ((const float4*)bary)[q * 3 + 1];
    const float4 bv2 = ((const float4*)bary)[q * 3 + 2];

    const float w0[4] = {bv0.x, bv0.w, bv1.z, bv2.y};
    const float w1[4] = {bv0.y, bv1.x, bv1.w, bv2.z};
    const float w2[4] = {bv0.z, bv1.y, bv2.x, bv2.w};
    const int  tid[4] = {t4.x, t4.y, t4.z, t4.w};

    const float* __restrict__ cb = colors + (long long)b * (3 * NVERT);

    float r[4], g[4], bl[4], a[4];
#pragma unroll
    for (int i = 0; i < 4; ++i) {
        const int t  = tid[i];
        const int v0 = tris[3 * t + 0];
        const int v1 = tris[3 * t + 1];
        const int v2 = tris[3 * t + 2];
        const float* c0 = cb + 3 * v0;
        const float* c1 = cb + 3 * v1;
        const float* c2 = cb + 3 * v2;
        const float u0 = w0[i], u1 = w1[i], u2 = w2[i];
        r[i]  = fminf(fmaxf(c0[0] * u0 + c1[0] * u1 + c2[0] * u2, 0.0f), 1.0f);
        g[i]  = fminf(fmaxf(c0[1] * u0 + c1[1] * u1 + c2[1] * u2, 0.0f), 1.0f);
        bl[i] = fminf(fmaxf(c0[2] * u0 + c1[2] * u1 + c2[2] * u2, 0.0f), 1.0f);
        a[i]  = fminf(fmaxf(2.0f * (u0 + u1 + u2), 0.0f), 1.0f);
    }

    float* img = out + (long long)b * (3 * HWPIX) + hw;
    ((float4*)(img            ))[0] = make_float4(r[0],  r[1],  r[2],  r[3]);
    ((float4*)(img +     HWPIX))[0] = make_float4(g[0],  g[1],  g[2],  g[3]);
    ((float4*)(img + 2 * HWPIX))[0] = make_float4(bl[0], bl[1], bl[2], bl[3]);

    float* al = out + (long long)BATCH * 3 * HWPIX + (long long)b * HWPIX + hw;
    ((float4*)al)[0] = make_float4(a[0], a[1], a[2], a[3]);
}

extern "C" void kernel_launch(void* const* d_in, const int* in_sizes, int n_in,
                              void* d_out, int out_size, void* d_ws, size_t ws_size,
                              hipStream_t stream) {
    const int*   tids   = (const int*)  d_in[0];
    const float* bary   = (const float*)d_in[1];
    const float* colors = (const float*)d_in[2];
    const int*   tris   = (const int*)  d_in[3];
    float*       out    = (float*)      d_out;

    const int quads = (BATCH * HWPIX) / 4;  // 2,097,152
    const int block = 256;
    const int grid  = quads / block;        // 8192

    const size_t tab_bytes = (size_t)BATCH * NTRI * 3 * sizeof(float4);  // ~27.2 MB
    if (ws_size >= tab_bytes) {
        float4* tab = (float4*)d_ws;
        dim3 pgrid((NTRI + 255) / 256, BATCH, 1);
        build_tritab<<<pgrid, 256, 0, stream>>>(colors, tris, tab);
        raster_tab_kernel<<<grid, block, 0, stream>>>(tids, bary, tab, out);
    } else {
        raster_kernel<<<grid, block, 0, stream>>>(tids, bary, colors, tris, out);
    }
}

// Round 3
// 288.617 us; speedup vs baseline: 1.1963x; 1.1963x over previous
//
#include <hip/hip_runtime.h>

// Problem constants: B=8, H=W=1024, V=35709, T=70789
#define BATCH 8
#define HWPIX (1024 * 1024)
#define NVERT 35709
#define NTRI  70789

// ---------------------------------------------------------------------------
// Prep: per-(batch,triangle) record of the 3 corner colors quantized to u8,
// packed into 16 B (one uint4). Layout:
//   w.x = c0.r | c0.g<<8 | c0.b<<16 | c1.r<<24
//   w.y = c1.g | c1.b<<8 | c2.r<<16 | c2.g<<24
//   w.z = c2.b
//   w.w = unused
// Table: [B, T] uint4 = 9.06 MB (1.13 MB per batch -> L2-resident per XCD).
// ---------------------------------------------------------------------------
__device__ __forceinline__ unsigned q8(float x) {
    float v = x * 255.0f + 0.5f;
    v = fminf(fmaxf(v, 0.0f), 255.0f);
    return (unsigned)v;
}

__global__ __launch_bounds__(256) void build_tritab_u8(
    const float* __restrict__ colors,  // [B,V,3]
    const int*   __restrict__ tris,    // [T,3]
    uint4*       __restrict__ tab)     // [B,T]
{
    const int t = blockIdx.x * blockDim.x + threadIdx.x;
    const int b = blockIdx.y;
    if (t >= NTRI) return;
    const int v0 = tris[3 * t + 0];
    const int v1 = tris[3 * t + 1];
    const int v2 = tris[3 * t + 2];
    const float* cb = colors + (long long)b * (3 * NVERT);
    const float* c0 = cb + 3 * v0;
    const float* c1 = cb + 3 * v1;
    const float* c2 = cb + 3 * v2;
    uint4 w;
    w.x = q8(c0[0]) | (q8(c0[1]) << 8) | (q8(c0[2]) << 16) | (q8(c1[0]) << 24);
    w.y = q8(c1[1]) | (q8(c1[2]) << 8) | (q8(c2[0]) << 16) | (q8(c2[1]) << 24);
    w.z = q8(c2[2]);
    w.w = 0u;
    tab[(long long)b * NTRI + t] = w;
}

// ---------------------------------------------------------------------------
// Main: one thread = 4 horizontally-adjacent pixels; exactly ONE uint4 gather
// per pixel. blockIdx.x & 7 selects the batch so each XCD (round-robin block
// dispatch) keeps a single 1.13 MB batch sub-table hot in its L2.
// ---------------------------------------------------------------------------
__global__ __launch_bounds__(256) void raster_u8_kernel(
    const int*   __restrict__ tids,   // [B,H,W]
    const float* __restrict__ bary,   // [B,H,W,3]
    const uint4* __restrict__ tab,    // [B,T]
    float*       __restrict__ out)    // images [B,3,H,W] ++ alphas [B,1,H,W]
{
    const int b   = blockIdx.x & 7;                 // batch -> XCD affinity
    const int blk = blockIdx.x >> 3;                // 0..1023 within batch
    const long long q  = (long long)b * (HWPIX / 4) + (long long)blk * blockDim.x + threadIdx.x;
    const int hw = (int)((q << 2) & (HWPIX - 1));

    const int4 t4 = ((const int4*)tids)[q];

    const float4 bv0 = ((const float4*)bary)[q * 3 + 0];
    const float4 bv1 = ((const float4*)bary)[q * 3 + 1];
    const float4 bv2 = ((const float4*)bary)[q * 3 + 2];

    const float w0[4] = {bv0.x, bv0.w, bv1.z, bv2.y};
    const float w1[4] = {bv0.y, bv1.x, bv1.w, bv2.z};
    const float w2[4] = {bv0.z, bv1.y, bv2.x, bv2.w};
    const int  tid[4] = {t4.x, t4.y, t4.z, t4.w};

    const uint4* tb = tab + (long long)b * NTRI;

    float r[4], g[4], bl[4], a[4];
#pragma unroll
    for (int i = 0; i < 4; ++i) {
        const uint4 w = tb[tid[i]];
        const float s0 = w0[i] * (1.0f / 255.0f);
        const float s1 = w1[i] * (1.0f / 255.0f);
        const float s2 = w2[i] * (1.0f / 255.0f);
        const float c0r = (float)( w.x        & 0xff);
        const float c0g = (float)((w.x >>  8) & 0xff);
        const float c0b = (float)((w.x >> 16) & 0xff);
        const float c1r = (float)( w.x >> 24        );
        const float c1g = (float)( w.y        & 0xff);
        const float c1b = (float)((w.y >>  8) & 0xff);
        const float c2r = (float)((w.y >> 16) & 0xff);
        const float c2g = (float)( w.y >> 24        );
        const float c2b = (float)( w.z        & 0xff);
        r[i]  = fminf(fmaxf(c0r * s0 + c1r * s1 + c2r * s2, 0.0f), 1.0f);
        g[i]  = fminf(fmaxf(c0g * s0 + c1g * s1 + c2g * s2, 0.0f), 1.0f);
        bl[i] = fminf(fmaxf(c0b * s0 + c1b * s1 + c2b * s2, 0.0f), 1.0f);
        a[i]  = fminf(fmaxf(2.0f * (w0[i] + w1[i] + w2[i]), 0.0f), 1.0f);
    }

    float* img = out + (long long)b * (3 * HWPIX) + hw;
    ((float4*)(img            ))[0] = make_float4(r[0],  r[1],  r[2],  r[3]);
    ((float4*)(img +     HWPIX))[0] = make_float4(g[0],  g[1],  g[2],  g[3]);
    ((float4*)(img + 2 * HWPIX))[0] = make_float4(bl[0], bl[1], bl[2], bl[3]);

    float* al = out + (long long)BATCH * 3 * HWPIX + (long long)b * HWPIX + hw;
    ((float4*)al)[0] = make_float4(a[0], a[1], a[2], a[3]);
}

// ---------------------------------------------------------------------------
// Fallback: direct two-level gather (R1), used only if ws is too small.
// ---------------------------------------------------------------------------
__global__ __launch_bounds__(256) void raster_kernel(
    const int*   __restrict__ tids,
    const float* __restrict__ bary,
    const float* __restrict__ colors,
    const int*   __restrict__ tris,
    float*       __restrict__ out)
{
    const long long q  = (long long)blockIdx.x * blockDim.x + threadIdx.x;
    const long long p0 = q << 2;
    const int b  = (int)(p0 >> 20);
    const int hw = (int)(p0 & (HWPIX - 1));

    const int4 t4 = ((const int4*)tids)[q];
    const float4 bv0 = ((const float4*)bary)[q * 3 + 0];
    const float4 bv1 = ((const float4*)bary)[q * 3 + 1];
    const float4 bv2 = ((const float4*)bary)[q * 3 + 2];

    const float w0[4] = {bv0.x, bv0.w, bv1.z, bv2.y};
    const float w1[4] = {bv0.y, bv1.x, bv1.w, bv2.z};
    const float w2[4] = {bv0.z, bv1.y, bv2.x, bv2.w};
    const int  tid[4] = {t4.x, t4.y, t4.z, t4.w};

    const float* __restrict__ cb = colors + (long long)b * (3 * NVERT);

    float r[4], g[4], bl[4], a[4];
#pragma unroll
    for (int i = 0; i < 4; ++i) {
        const int t  = tid[i];
        const int v0 = tris[3 * t + 0];
        const int v1 = tris[3 * t + 1];
        const int v2 = tris[3 * t + 2];
        const float* c0 = cb + 3 * v0;
        const float* c1 = cb + 3 * v1;
        const float* c2 = cb + 3 * v2;
        const float u0 = w0[i], u1 = w1[i], u2 = w2[i];
        r[i]  = fminf(fmaxf(c0[0] * u0 + c1[0] * u1 + c2[0] * u2, 0.0f), 1.0f);
        g[i]  = fminf(fmaxf(c0[1] * u0 + c1[1] * u1 + c2[1] * u2, 0.0f), 1.0f);
        bl[i] = fminf(fmaxf(c0[2] * u0 + c1[2] * u1 + c2[2] * u2, 0.0f), 1.0f);
        a[i]  = fminf(fmaxf(2.0f * (u0 + u1 + u2), 0.0f), 1.0f);
    }

    float* img = out + (long long)b * (3 * HWPIX) + hw;
    ((float4*)(img            ))[0] = make_float4(r[0],  r[1],  r[2],  r[3]);
    ((float4*)(img +     HWPIX))[0] = make_float4(g[0],  g[1],  g[2],  g[3]);
    ((float4*)(img + 2 * HWPIX))[0] = make_float4(bl[0], bl[1], bl[2], bl[3]);

    float* al = out + (long long)BATCH * 3 * HWPIX + (long long)b * HWPIX + hw;
    ((float4*)al)[0] = make_float4(a[0], a[1], a[2], a[3]);
}

extern "C" void kernel_launch(void* const* d_in, const int* in_sizes, int n_in,
                              void* d_out, int out_size, void* d_ws, size_t ws_size,
                              hipStream_t stream) {
    const int*   tids   = (const int*)  d_in[0];
    const float* bary   = (const float*)d_in[1];
    const float* colors = (const float*)d_in[2];
    const int*   tris   = (const int*)  d_in[3];
    float*       out    = (float*)      d_out;

    const int quads = (BATCH * HWPIX) / 4;  // 2,097,152
    const int block = 256;
    const int grid  = quads / block;        // 8192

    const size_t tab_bytes = (size_t)BATCH * NTRI * sizeof(uint4);  // ~9.06 MB
    if (ws_size >= tab_bytes) {
        uint4* tab = (uint4*)d_ws;
        dim3 pgrid((NTRI + 255) / 256, BATCH, 1);
        build_tritab_u8<<<pgrid, 256, 0, stream>>>(colors, tris, tab);
        raster_u8_kernel<<<grid, block, 0, stream>>>(tids, bary, tab, out);
    } else {
        raster_kernel<<<grid, block, 0, stream>>>(tids, bary, colors, tris, out);
    }
}